// Round 4
// baseline (117.872 us; speedup 1.0000x reference)
//
#include <hip/hip_runtime.h>

#define NROW 8192
#define DIM  1447
#define HD   64
#define WK   1472      // 23*64: zero-padded K for pre-converted W
#define NSTEP 23
#define LD65 65        // scan row layout [q][65]

typedef __attribute__((ext_vector_type(8))) short bf16x8;
typedef __attribute__((ext_vector_type(4))) float f32x4;

__device__ __forceinline__ float lrelu(float v) { return v >= 0.f ? v : 0.01f * v; }

__device__ __forceinline__ unsigned short f2bf(float f) {
  unsigned u = __float_as_uint(f);
  u = u + 0x7fffu + ((u >> 16) & 1u);   // RNE
  return (unsigned short)(u >> 16);
}
__device__ __forceinline__ float bf2f(unsigned short s) {
  return __uint_as_float((unsigned)s << 16);
}

// monotone float<->uint encoding for atomicMax on f32
__device__ __forceinline__ unsigned enc(float f) {
  unsigned u = __float_as_uint(f);
  return (u & 0x80000000u) ? ~u : (u | 0x80000000u);
}
__device__ __forceinline__ float dec(unsigned k) {
  unsigned u = (k & 0x80000000u) ? (k & 0x7fffffffu) : ~k;
  return __uint_as_float(u);
}

// K0: block 0: u1/u2/c1/c2 prep + init M1.  blocks 1..368: W_fc -> bf16 hi/lo (K-padded)
__global__ void k_prep(const float* __restrict__ Wtr, const float* __restrict__ btr,
                       const float* __restrict__ a, const float* __restrict__ Wfc,
                       float* __restrict__ u12, unsigned* __restrict__ m1slot,
                       unsigned short* __restrict__ Wh, unsigned short* __restrict__ Wl) {
  int t = threadIdx.x;
  int b = blockIdx.x;
  if (b == 0) {
    if (t < 64) {
      float u1 = 0.f, u2 = 0.f;
      for (int o = 0; o < 64; ++o) {
        float w = Wtr[o * 64 + t];
        u1 += w * a[o];
        u2 += w * a[64 + o];
      }
      u12[t] = u1; u12[64 + t] = u2;
      if (t == 0) {
        float c1 = 0.f, c2 = 0.f;
        for (int o = 0; o < 64; ++o) { c1 += btr[o] * a[o]; c2 += btr[o] * a[64 + o]; }
        u12[128] = c1; u12[129] = c2;
        *m1slot = 0u;
      }
    }
  } else {
    int idx = (b - 1) * 256 + t;          // < 64*WK
    int c = idx / WK, k = idx - c * WK;
    float v = (k < DIM) ? Wfc[c * DIM + k] : 0.f;
    unsigned short hi = f2bf(v);
    Wh[idx] = hi;
    Wl[idx] = f2bf(v - bf2f(hi));
  }
}

// K1: h = lrelu(x @ W_fc.T + b_fc) via split-bf16 MFMA; fused s1/s2/max epilogue.
// 256 blocks x 512 thr (8 waves). Tile 32 rows x 64 cols, BK=64, double-buffered LDS.
__global__ __launch_bounds__(512) void k_gemm1(const float* __restrict__ x,
    const unsigned short* __restrict__ Wh, const unsigned short* __restrict__ Wl,
    const float* __restrict__ bfc, const float* __restrict__ u12,
    float* __restrict__ h, float* __restrict__ s1, float* __restrict__ s2,
    unsigned* __restrict__ m1slot) {
  __shared__ alignas(16) unsigned short Ah[2][32][72], Al[2][32][72];
  __shared__ alignas(16) unsigned short Bh[2][64][72], Bl[2][64][72];
  __shared__ float Hs[32][68];
  int t = threadIdx.x;
  int rb = blockIdx.x;
  int sxr = t >> 4;            // x stage: row 0..31
  int sxk = (t & 15) * 4;      // k 0..60
  int swc = t >> 3;            // W stage: col 0..63
  int swk = (t & 7) * 8;       // k 0..56
  int wv = t >> 6;             // wave 0..7
  int rg = (wv & 1) * 16;
  int cg = (wv >> 1) * 16;
  int l = t & 63;
  int l15 = l & 15;
  int l4 = l >> 4;

  const float* xrow = x + (size_t)(rb * 32 + sxr) * DIM;
  const unsigned short* whrow = Wh + (size_t)swc * WK + swk;
  const unsigned short* wlrow = Wl + (size_t)swc * WK + swk;

  f32x4 acc = {0.f, 0.f, 0.f, 0.f};
  float x0, x1, x2, x3;
  int4 wh4, wl4;

  x0 = xrow[sxk]; x1 = xrow[sxk + 1]; x2 = xrow[sxk + 2]; x3 = xrow[sxk + 3];
  wh4 = *(const int4*)&whrow[0];
  wl4 = *(const int4*)&wlrow[0];
  {
    unsigned short h0 = f2bf(x0), h1 = f2bf(x1), h2 = f2bf(x2), h3 = f2bf(x3);
    unsigned short m0 = f2bf(x0 - bf2f(h0)), m1_ = f2bf(x1 - bf2f(h1)),
                   m2 = f2bf(x2 - bf2f(h2)), m3 = f2bf(x3 - bf2f(h3));
    uint2 ph, pl;
    ph.x = (unsigned)h0 | ((unsigned)h1 << 16);
    ph.y = (unsigned)h2 | ((unsigned)h3 << 16);
    pl.x = (unsigned)m0 | ((unsigned)m1_ << 16);
    pl.y = (unsigned)m2 | ((unsigned)m3 << 16);
    *(uint2*)&Ah[0][sxr][sxk] = ph;
    *(uint2*)&Al[0][sxr][sxk] = pl;
    *(int4*)&Bh[0][swc][swk] = wh4;
    *(int4*)&Bl[0][swc][swk] = wl4;
  }
  __syncthreads();

  for (int s = 0; s < NSTEP; ++s) {
    int buf = s & 1;
    if (s + 1 < NSTEP) {               // issue next-step global loads early
      int kt = (s + 1) * 64;
      int kg = kt + sxk;
      x0 = (kg     < DIM) ? xrow[kg]     : 0.f;
      x1 = (kg + 1 < DIM) ? xrow[kg + 1] : 0.f;
      x2 = (kg + 2 < DIM) ? xrow[kg + 2] : 0.f;
      x3 = (kg + 3 < DIM) ? xrow[kg + 3] : 0.f;
      wh4 = *(const int4*)&whrow[kt];
      wl4 = *(const int4*)&wlrow[kt];
    }
#pragma unroll
    for (int c = 0; c < 2; ++c) {
      int kc = c * 32 + l4 * 8;
      bf16x8 fah = *(const bf16x8*)&Ah[buf][rg + l15][kc];
      bf16x8 fal = *(const bf16x8*)&Al[buf][rg + l15][kc];
      bf16x8 fbh = *(const bf16x8*)&Bh[buf][cg + l15][kc];
      bf16x8 fbl = *(const bf16x8*)&Bl[buf][cg + l15][kc];
      acc = __builtin_amdgcn_mfma_f32_16x16x32_bf16(fah, fbh, acc, 0, 0, 0);
      acc = __builtin_amdgcn_mfma_f32_16x16x32_bf16(fah, fbl, acc, 0, 0, 0);
      acc = __builtin_amdgcn_mfma_f32_16x16x32_bf16(fal, fbh, acc, 0, 0, 0);
    }
    if (s + 1 < NSTEP) {
      int nb = buf ^ 1;
      unsigned short h0 = f2bf(x0), h1 = f2bf(x1), h2 = f2bf(x2), h3 = f2bf(x3);
      unsigned short m0 = f2bf(x0 - bf2f(h0)), m1_ = f2bf(x1 - bf2f(h1)),
                     m2 = f2bf(x2 - bf2f(h2)), m3 = f2bf(x3 - bf2f(h3));
      uint2 ph, pl;
      ph.x = (unsigned)h0 | ((unsigned)h1 << 16);
      ph.y = (unsigned)h2 | ((unsigned)h3 << 16);
      pl.x = (unsigned)m0 | ((unsigned)m1_ << 16);
      pl.y = (unsigned)m2 | ((unsigned)m3 << 16);
      *(uint2*)&Ah[nb][sxr][sxk] = ph;
      *(uint2*)&Al[nb][sxr][sxk] = pl;
      *(int4*)&Bh[nb][swc][swk] = wh4;
      *(int4*)&Bl[nb][swc][swk] = wl4;
    }
    __syncthreads();
  }

  // epilogue: bias + lrelu; store h; stage into LDS for fused s1/s2.
  // D layout: col = lane&15, row = 4*(lane>>4)+reg  [m89-verified]
  int col = cg + l15;
  float bb = bfc[col];
  int lrow0 = rg + l4 * 4;
#pragma unroll
  for (int r = 0; r < 4; ++r) {
    float hv = lrelu(acc[r] + bb);
    h[(size_t)(rb * 32 + lrow0 + r) * HD + col] = hv;
    Hs[lrow0 + r][col] = hv;
  }
  __syncthreads();
  if (t < 256) {
    int row = t >> 3, cg8 = (t & 7) * 8;
    float d1 = 0.f, d2 = 0.f;
#pragma unroll
    for (int jj = 0; jj < 8; ++jj) {
      int c = cg8 + jj;
      float v = Hs[row][c];
      d1 += v * u12[c];
      d2 += v * u12[64 + c];
    }
    d1 += __shfl_xor(d1, 1); d1 += __shfl_xor(d1, 2); d1 += __shfl_xor(d1, 4);
    d2 += __shfl_xor(d2, 1); d2 += __shfl_xor(d2, 2); d2 += __shfl_xor(d2, 4);
    float sv1 = d1 + u12[128];
    float sv2 = d2 + u12[129];
    int gr = rb * 32 + row;
    if ((t & 7) == 0) { s1[gr] = sv1; s2[gr] = sv2; }
    float m = sv1;
    m = fmaxf(m, __shfl_xor(m, 8));
    m = fmaxf(m, __shfl_xor(m, 16));
    m = fmaxf(m, __shfl_xor(m, 32));
    if ((t & 63) == 0) atomicMax(m1slot, enc(m));
  }
}

// K2: exact-rank sort (no atomics). 256 blocks x 256 thr; block owns 32 j's;
// 8 threads/j; s1 staged in 4KB LDS passes; 1024 compares/thread.
__global__ __launch_bounds__(256) void k_sort(const float* __restrict__ s1,
                                              float* __restrict__ s1s,
                                              int* __restrict__ inv) {
  __shared__ alignas(16) float buf[1024];
  int t = threadIdx.x;
  int jl = t >> 3, sub = t & 7;
  int j = blockIdx.x * 32 + jl;
  float my = s1[j];
  int cnt = 0;
  for (int p = 0; p < 8; ++p) {
#pragma unroll
    for (int m = 0; m < 4; ++m) buf[t + m * 256] = s1[p * 1024 + t + m * 256];
    __syncthreads();
    int base = p * 1024 + sub * 128;
    const float* bb = &buf[sub * 128];
#pragma unroll 8
    for (int e = 0; e < 128; e += 4) {
      float4 v = *(const float4*)&bb[e];
      cnt += (v.x < my) + (v.y < my) + (v.z < my) + (v.w < my);
      cnt += (v.x == my && (base + e)     < j);
      cnt += (v.y == my && (base + e + 1) < j);
      cnt += (v.z == my && (base + e + 2) < j);
      cnt += (v.w == my && (base + e + 3) < j);
    }
    __syncthreads();
  }
  cnt += __shfl_xor(cnt, 1);
  cnt += __shfl_xor(cnt, 2);
  cnt += __shfl_xor(cnt, 4);
  if (sub == 0) { inv[cnt] = j; s1s[cnt] = my; }
}

// K3: per-column prefix(B)/suffix(A) scans over sorted order, gathering h
// directly (h is L2-resident). Output layout [q][65] for coalesced k_final reads.
__global__ __launch_bounds__(512) void k_scan(const float* __restrict__ s1s,
                                              const int* __restrict__ inv,
                                              const float* __restrict__ h,
                                              const unsigned* __restrict__ m1slot,
                                              float* __restrict__ SufA,
                                              float* __restrict__ PreB) {
  int t = threadIdx.x;
  int c = blockIdx.x % 65;
  int br = blockIdx.x / 65;  // 0 = A (suffix, e^{s1-M1}), 1 = B (prefix, e^{0.01 s1})
  float M1 = dec(*m1slot);
  float vals[16];
  int qb = t * 16;
#pragma unroll
  for (int e = 0; e < 16; ++e) {
    int q = qb + e;
    int r = br ? q : (NROW - 1 - q);
    float s = s1s[r];
    float w = br ? __expf(0.01f * s) : __expf(s - M1);
    float hv = 1.0f;
    if (c < 64) { int j = inv[r]; hv = h[(size_t)j * HD + c]; }
    vals[e] = w * hv;
  }
  float sum = 0.f;
#pragma unroll
  for (int e = 0; e < 16; ++e) sum += vals[e];
  int lane = t & 63, wid = t >> 6;
  float sc = sum;
#pragma unroll
  for (int off = 1; off < 64; off <<= 1) {
    float o = __shfl_up(sc, off);
    if (lane >= off) sc += o;
  }
  __shared__ float wt[8];
  if (lane == 63) wt[wid] = sc;
  __syncthreads();
  float woff = 0.f;
#pragma unroll
  for (int w = 0; w < 8; ++w)
    if (w < wid) woff += wt[w];
  float p = __shfl_up(sc, 1);
  float run = woff + (lane ? p : 0.f);
  if (br) {
#pragma unroll
    for (int e = 0; e < 16; ++e) {
      PreB[(size_t)(qb + e) * LD65 + c] = run;
      run += vals[e];
    }
    if (t == 511) PreB[(size_t)NROW * LD65 + c] = run;  // total
  } else {
#pragma unroll
    for (int e = 0; e < 16; ++e) {
      run += vals[e];
      SufA[(size_t)(NROW - 1 - (qb + e)) * LD65 + c] = run;
    }
    if (t == 0) SufA[(size_t)NROW * LD65 + c] = 0.f;
  }
}

// K4: per-row closed-form softmax combine + residual + W_f/lrelu + W_o.
// 256 blocks x 256 thr; each wave processes 8 rows with Wf row in registers.
__global__ __launch_bounds__(256) void k_final(const float* __restrict__ h,
    const float* __restrict__ s1s, const float* __restrict__ s2,
    const float* __restrict__ SufA, const float* __restrict__ PreB,
    const unsigned* __restrict__ m1slot, const float* __restrict__ Wf,
    const float* __restrict__ bf, const float* __restrict__ Wo,
    const float* __restrict__ bo, float* __restrict__ out) {
  int t = threadIdx.x;
  int lane = t & 63, wid = t >> 6;
  __shared__ float coarse[64];
  if (t < 64) coarse[t] = s1s[t * 128];
  __syncthreads();
  float4 wf[16];
  const float4* wrow = (const float4*)(Wf + (size_t)lane * HD);
#pragma unroll
  for (int q = 0; q < 16; ++q) wf[q] = wrow[q];
  float bfl = bf[lane], wol = Wo[lane], bo0 = bo[0];
  float M1 = dec(*m1slot);
  float myc = coarse[lane];

  for (int rr = 0; rr < 8; ++rr) {
    int i = blockIdx.x * 32 + wid * 8 + rr;
    float s2i = s2[i];
    float th = -s2i;
    float z = s2i + M1;
    float mi = lrelu(z);
    float cA = __expf(z - mi);
    float cB = __expf(0.01f * s2i - mi);
    int n1 = __popcll(__ballot(myc < th));
    int cnt = 0;
    if (n1 > 0) {
      int L = (n1 - 1) * 128;
      float v2 = s1s[L + 1 + 2 * lane];
      int n2 = __popcll(__ballot(v2 < th));
      cnt = L + 2 * n2;
      if (cnt < NROW && s1s[cnt] < th) cnt++;
    }
    const float* ra = SufA + (size_t)cnt * LD65;
    const float* rb = PreB + (size_t)cnt * LD65;
    float vA = ra[lane], vB = rb[lane];
    float zA = ra[64],  zB = rb[64];
    float Z = cA * zA + cB * zB;
    float h2 = (cA * vA + cB * vB) / Z + h[(size_t)i * HD + lane];
    float acc = bfl;
#pragma unroll
    for (int q = 0; q < 16; ++q) {
      float4 wv = wf[q];
      int c = q * 4;
      acc += wv.x * __shfl(h2, c) + wv.y * __shfl(h2, c + 1) +
             wv.z * __shfl(h2, c + 2) + wv.w * __shfl(h2, c + 3);
    }
    float h3 = lrelu(acc);
    float pv = h3 * wol;
#pragma unroll
    for (int off = 32; off > 0; off >>= 1) pv += __shfl_xor(pv, off);
    if (lane == 0) out[i] = pv + bo0;
  }
}

extern "C" void kernel_launch(void* const* d_in, const int* in_sizes, int n_in,
                              void* d_out, int out_size, void* d_ws, size_t ws_size,
                              hipStream_t stream) {
  const float* x   = (const float*)d_in[0];
  const float* Wfc = (const float*)d_in[1];
  const float* bfc = (const float*)d_in[2];
  const float* Wtr = (const float*)d_in[3];
  const float* btr = (const float*)d_in[4];
  const float* a   = (const float*)d_in[5];
  const float* Wf  = (const float*)d_in[6];
  const float* bf  = (const float*)d_in[7];
  const float* Wo  = (const float*)d_in[8];
  const float* bo  = (const float*)d_in[9];
  float* out = (float*)d_out;

  char* w = (char*)d_ws;
  size_t off = 0;
  auto alloc = [&](size_t bytes) -> void* {
    void* p = w + off;
    off = (off + bytes + 255) & ~(size_t)255;
    return p;
  };
  float* h      = (float*)alloc((size_t)NROW * HD * 4);
  float* s1     = (float*)alloc(NROW * 4);
  float* s2     = (float*)alloc(NROW * 4);
  float* u12    = (float*)alloc(130 * 4);
  unsigned* m1  = (unsigned*)alloc(4);
  int* inv      = (int*)alloc(NROW * 4);
  float* s1s    = (float*)alloc(NROW * 4);
  unsigned short* Wh = (unsigned short*)alloc((size_t)64 * WK * 2);
  unsigned short* Wl = (unsigned short*)alloc((size_t)64 * WK * 2);
  float* SufA   = (float*)alloc((size_t)(NROW + 1) * LD65 * 4);
  float* PreB   = (float*)alloc((size_t)(NROW + 1) * LD65 * 4);
  (void)in_sizes; (void)n_in; (void)out_size; (void)ws_size;

  k_prep<<<1 + (64 * WK) / 256, 256, 0, stream>>>(Wtr, btr, a, Wfc, u12, m1, Wh, Wl);
  k_gemm1<<<NROW / 32, 512, 0, stream>>>(x, Wh, Wl, bfc, u12, h, s1, s2, m1);
  k_sort<<<NROW / 32, 256, 0, stream>>>(s1, s1s, inv);
  k_scan<<<130, 512, 0, stream>>>(s1s, inv, h, m1, SufA, PreB);
  k_final<<<NROW / 32, 256, 0, stream>>>(h, s1s, s2, SufA, PreB, m1, Wf, bf, Wo, bo, out);
}

// Round 5
// 117.371 us; speedup vs baseline: 1.0043x; 1.0043x over previous
//
#include <hip/hip_runtime.h>

#define NROW 8192
#define DIM  1447
#define HD   64
#define WK   1472      // 46*32: zero-padded K for pre-converted W
#define LD65 65        // scan row layout [q][65]

typedef __attribute__((ext_vector_type(8))) short bf16x8;
typedef __attribute__((ext_vector_type(4))) float f32x4;

__device__ __forceinline__ float lrelu(float v) { return v >= 0.f ? v : 0.01f * v; }

__device__ __forceinline__ unsigned short f2bf(float f) {
  unsigned u = __float_as_uint(f);
  u = u + 0x7fffu + ((u >> 16) & 1u);   // RNE
  return (unsigned short)(u >> 16);
}
__device__ __forceinline__ float bf2f(unsigned short s) {
  return __uint_as_float((unsigned)s << 16);
}

// monotone float<->uint encoding for atomicMax on f32
__device__ __forceinline__ unsigned enc(float f) {
  unsigned u = __float_as_uint(f);
  return (u & 0x80000000u) ? ~u : (u | 0x80000000u);
}
__device__ __forceinline__ float dec(unsigned k) {
  unsigned u = (k & 0x80000000u) ? (k & 0x7fffffffu) : ~k;
  return __uint_as_float(u);
}

__device__ __forceinline__ void cvt_frag(const float* xv, bf16x8& ah, bf16x8& al) {
  union { bf16x8 v; unsigned u[4]; } H, L;
#pragma unroll
  for (int q = 0; q < 4; ++q) {
    unsigned short h0 = f2bf(xv[2 * q]),     h1 = f2bf(xv[2 * q + 1]);
    unsigned short l0 = f2bf(xv[2 * q]     - bf2f(h0));
    unsigned short l1 = f2bf(xv[2 * q + 1] - bf2f(h1));
    H.u[q] = (unsigned)h0 | ((unsigned)h1 << 16);
    L.u[q] = (unsigned)l0 | ((unsigned)l1 << 16);
  }
  ah = H.v; al = L.v;
}

union BU { int4 i; bf16x8 v; };

// K0: block 0: u1/u2/c1/c2 prep + init M1.  blocks 1..368: W_fc -> bf16 hi/lo (K-padded)
__global__ void k_prep(const float* __restrict__ Wtr, const float* __restrict__ btr,
                       const float* __restrict__ a, const float* __restrict__ Wfc,
                       float* __restrict__ u12, unsigned* __restrict__ m1slot,
                       unsigned short* __restrict__ Wh, unsigned short* __restrict__ Wl) {
  int t = threadIdx.x;
  int b = blockIdx.x;
  if (b == 0) {
    if (t < 64) {
      float u1 = 0.f, u2 = 0.f;
      for (int o = 0; o < 64; ++o) {
        float w = Wtr[o * 64 + t];
        u1 += w * a[o];
        u2 += w * a[64 + o];
      }
      u12[t] = u1; u12[64 + t] = u2;
      if (t == 0) {
        float c1 = 0.f, c2 = 0.f;
        for (int o = 0; o < 64; ++o) { c1 += btr[o] * a[o]; c2 += btr[o] * a[64 + o]; }
        u12[128] = c1; u12[129] = c2;
        *m1slot = 0u;
      }
    }
  } else {
    int idx = (b - 1) * 256 + t;          // < 64*WK
    int c = idx / WK, k = idx - c * WK;
    float v = (k < DIM) ? Wfc[c * DIM + k] : 0.f;
    unsigned short hi = f2bf(v);
    Wh[idx] = hi;
    Wl[idx] = f2bf(v - bf2f(hi));
  }
}

// K1: h = lrelu(x @ W_fc.T + b_fc) via split-bf16 MFMA, LDS-free, barrier-free K-loop.
// 256 blocks x 8 waves; wave owns one 16x16 tile; fragments loaded straight from global.
// Fused s1/s2/max epilogue (one barrier at the end).
__global__ __launch_bounds__(512) void k_gemm(const float* __restrict__ x,
    const unsigned short* __restrict__ Wh, const unsigned short* __restrict__ Wl,
    const float* __restrict__ bfc, const float* __restrict__ u12,
    float* __restrict__ h, float* __restrict__ s1, float* __restrict__ s2,
    unsigned* __restrict__ m1slot) {
  __shared__ float Pd1[32][4], Pd2[32][4];
  int t = threadIdx.x;
  int wv = t >> 6;          // 0..7
  int l = t & 63;
  int l15 = l & 15, l4 = l >> 4;
  int rgl = wv >> 2;        // rowgroup within block: 0/1
  int cg = wv & 3;          // colgroup 0..3
  int R0 = blockIdx.x * 32 + rgl * 16;
  int C0 = cg * 16;
  int ab = l4 * 8;          // k-offset within fragment

  const float* xp = x + (size_t)(R0 + l15) * DIM;
  const unsigned short* whp = Wh + (size_t)(C0 + l15) * WK;
  const unsigned short* wlp = Wl + (size_t)(C0 + l15) * WK;

  f32x4 acc = {0.f, 0.f, 0.f, 0.f};
  float xc[8], xn[8];
  int4 whc, wlc, whn, wln;

#pragma unroll
  for (int e = 0; e < 8; ++e) xc[e] = xp[ab + e];
  whc = *(const int4*)(whp + ab);
  wlc = *(const int4*)(wlp + ab);

  for (int s = 0; s < 45; ++s) {
    int kn = (s + 1) * 32 + ab;
    if (s < 44) {
#pragma unroll
      for (int e = 0; e < 8; ++e) xn[e] = xp[kn + e];
    } else {
#pragma unroll
      for (int e = 0; e < 8; ++e) xn[e] = (kn + e < DIM) ? xp[kn + e] : 0.f;
    }
    whn = *(const int4*)(whp + kn);
    wln = *(const int4*)(wlp + kn);
    bf16x8 ah, al;
    cvt_frag(xc, ah, al);
    BU bh, bl; bh.i = whc; bl.i = wlc;
    acc = __builtin_amdgcn_mfma_f32_16x16x32_bf16(ah, bh.v, acc, 0, 0, 0);
    acc = __builtin_amdgcn_mfma_f32_16x16x32_bf16(ah, bl.v, acc, 0, 0, 0);
    acc = __builtin_amdgcn_mfma_f32_16x16x32_bf16(al, bh.v, acc, 0, 0, 0);
#pragma unroll
    for (int e = 0; e < 8; ++e) xc[e] = xn[e];
    whc = whn; wlc = wln;
  }
  {
    bf16x8 ah, al;
    cvt_frag(xc, ah, al);
    BU bh, bl; bh.i = whc; bl.i = wlc;
    acc = __builtin_amdgcn_mfma_f32_16x16x32_bf16(ah, bh.v, acc, 0, 0, 0);
    acc = __builtin_amdgcn_mfma_f32_16x16x32_bf16(ah, bl.v, acc, 0, 0, 0);
    acc = __builtin_amdgcn_mfma_f32_16x16x32_bf16(al, bh.v, acc, 0, 0, 0);
  }

  // epilogue: bias + lrelu + store h; fused partial s1/s2 dots.
  // D layout: col = lane&15, row = (lane>>4)*4 + reg  [m89-verified]
  int col = C0 + l15;
  float bb = bfc[col];
  float u1c = u12[col], u2c = u12[64 + col];
#pragma unroll
  for (int r = 0; r < 4; ++r) {
    int row = R0 + l4 * 4 + r;
    float hv = lrelu(acc[r] + bb);
    h[(size_t)row * HD + col] = hv;
    float d1 = hv * u1c, d2 = hv * u2c;
    d1 += __shfl_xor(d1, 1); d1 += __shfl_xor(d1, 2);
    d1 += __shfl_xor(d1, 4); d1 += __shfl_xor(d1, 8);
    d2 += __shfl_xor(d2, 1); d2 += __shfl_xor(d2, 2);
    d2 += __shfl_xor(d2, 4); d2 += __shfl_xor(d2, 8);
    if (l15 == 0) {
      int rl = rgl * 16 + l4 * 4 + r;
      Pd1[rl][cg] = d1;
      Pd2[rl][cg] = d2;
    }
  }
  __syncthreads();
  if (t < 32) {
    float d1 = Pd1[t][0] + Pd1[t][1] + Pd1[t][2] + Pd1[t][3] + u12[128];
    float d2 = Pd2[t][0] + Pd2[t][1] + Pd2[t][2] + Pd2[t][3] + u12[129];
    int gr = blockIdx.x * 32 + t;
    s1[gr] = d1;
    s2[gr] = d2;
    float m = d1;
    m = fmaxf(m, __shfl_xor(m, 1));
    m = fmaxf(m, __shfl_xor(m, 2));
    m = fmaxf(m, __shfl_xor(m, 4));
    m = fmaxf(m, __shfl_xor(m, 8));
    m = fmaxf(m, __shfl_xor(m, 16));
    if (t == 0) atomicMax(m1slot, enc(m));
  }
}

// K2: exact-rank sort (no atomics). 256 blocks x 512 thr; block owns 32 j's;
// 16 threads/j; s1 staged in 4KB LDS passes; 512 compares/thread.
__global__ __launch_bounds__(512) void k_sort(const float* __restrict__ s1,
                                              float* __restrict__ s1s,
                                              int* __restrict__ inv) {
  __shared__ alignas(16) float buf[1024];
  int t = threadIdx.x;
  int jl = t >> 4, sub = t & 15;
  int j = blockIdx.x * 32 + jl;
  float my = s1[j];
  int cnt = 0;
  for (int p = 0; p < 8; ++p) {
    buf[t] = s1[p * 1024 + t];
    buf[t + 512] = s1[p * 1024 + t + 512];
    __syncthreads();
    int base = p * 1024 + sub * 64;
    const float* bb = &buf[sub * 64];
#pragma unroll 4
    for (int e = 0; e < 64; e += 4) {
      float4 v = *(const float4*)&bb[e];
      cnt += (v.x < my) + (v.y < my) + (v.z < my) + (v.w < my);
      cnt += (v.x == my && (base + e)     < j);
      cnt += (v.y == my && (base + e + 1) < j);
      cnt += (v.z == my && (base + e + 2) < j);
      cnt += (v.w == my && (base + e + 3) < j);
    }
    __syncthreads();
  }
  cnt += __shfl_xor(cnt, 1);
  cnt += __shfl_xor(cnt, 2);
  cnt += __shfl_xor(cnt, 4);
  cnt += __shfl_xor(cnt, 8);
  if (sub == 0) { inv[cnt] = j; s1s[cnt] = my; }
}

// K3: hsT[c][r] = h[inv[r]][c]  (coalesced gather + LDS transpose)
__global__ __launch_bounds__(256) void k_trans(const float* __restrict__ h,
                                               const int* __restrict__ inv,
                                               float* __restrict__ hsT) {
  __shared__ float tile[64][65];
  int t = threadIdx.x;
  int r0 = blockIdx.x * 64;
  int rr = t >> 2;
  int cseg = (t & 3) * 16;
  int j = inv[r0 + rr];
#pragma unroll
  for (int q = 0; q < 4; ++q) {
    float4 v = *(const float4*)&h[(size_t)j * HD + cseg + q * 4];
    tile[rr][cseg + q * 4]     = v.x;
    tile[rr][cseg + q * 4 + 1] = v.y;
    tile[rr][cseg + q * 4 + 2] = v.z;
    tile[rr][cseg + q * 4 + 3] = v.w;
  }
  __syncthreads();
  int c = t >> 2;
  int rseg = (t & 3) * 16;
#pragma unroll
  for (int e = 0; e < 16; e += 4) {
    int r = rseg + e;
    float4 v = make_float4(tile[r][c], tile[r + 1][c], tile[r + 2][c], tile[r + 3][c]);
    *(float4*)&hsT[(size_t)c * NROW + r0 + r] = v;
  }
}

// K4: per-column prefix(B)/suffix(A) scans over sorted order (streaming hsT),
// output layout [q][65] for coalesced k_final reads.
__global__ __launch_bounds__(512) void k_scan(const float* __restrict__ s1s,
                                              const float* __restrict__ hsT,
                                              const unsigned* __restrict__ m1slot,
                                              float* __restrict__ SufA,
                                              float* __restrict__ PreB) {
  int t = threadIdx.x;
  int c = blockIdx.x % 65;
  int br = blockIdx.x / 65;  // 0 = A (suffix, e^{s1-M1}), 1 = B (prefix, e^{0.01 s1})
  float M1 = dec(*m1slot);
  const float* hc = hsT + (size_t)c * NROW;
  float vals[16];
  int qb = t * 16;
#pragma unroll
  for (int e = 0; e < 16; ++e) {
    int q = qb + e;
    int r = br ? q : (NROW - 1 - q);
    float s = s1s[r];
    float w = br ? __expf(0.01f * s) : __expf(s - M1);
    float hv = (c < 64) ? hc[r] : 1.0f;
    vals[e] = w * hv;
  }
  float sum = 0.f;
#pragma unroll
  for (int e = 0; e < 16; ++e) sum += vals[e];
  int lane = t & 63, wid = t >> 6;
  float sc = sum;
#pragma unroll
  for (int off = 1; off < 64; off <<= 1) {
    float o = __shfl_up(sc, off);
    if (lane >= off) sc += o;
  }
  __shared__ float wt[8];
  if (lane == 63) wt[wid] = sc;
  __syncthreads();
  float woff = 0.f;
#pragma unroll
  for (int w = 0; w < 8; ++w)
    if (w < wid) woff += wt[w];
  float p = __shfl_up(sc, 1);
  float run = woff + (lane ? p : 0.f);
  if (br) {
#pragma unroll
    for (int e = 0; e < 16; ++e) {
      PreB[(size_t)(qb + e) * LD65 + c] = run;
      run += vals[e];
    }
    if (t == 511) PreB[(size_t)NROW * LD65 + c] = run;  // total
  } else {
#pragma unroll
    for (int e = 0; e < 16; ++e) {
      run += vals[e];
      SufA[(size_t)(NROW - 1 - (qb + e)) * LD65 + c] = run;
    }
    if (t == 0) SufA[(size_t)NROW * LD65 + c] = 0.f;
  }
}

// K5: per-row closed-form softmax combine + residual + W_f/lrelu + W_o.
// 256 blocks x 256 thr; each wave processes 8 rows with Wf row in registers.
__global__ __launch_bounds__(256) void k_final(const float* __restrict__ h,
    const float* __restrict__ s1s, const float* __restrict__ s2,
    const float* __restrict__ SufA, const float* __restrict__ PreB,
    const unsigned* __restrict__ m1slot, const float* __restrict__ Wf,
    const float* __restrict__ bf, const float* __restrict__ Wo,
    const float* __restrict__ bo, float* __restrict__ out) {
  int t = threadIdx.x;
  int lane = t & 63, wid = t >> 6;
  __shared__ float coarse[64];
  if (t < 64) coarse[t] = s1s[t * 128];
  __syncthreads();
  float4 wf[16];
  const float4* wrow = (const float4*)(Wf + (size_t)lane * HD);
#pragma unroll
  for (int q = 0; q < 16; ++q) wf[q] = wrow[q];
  float bfl = bf[lane], wol = Wo[lane], bo0 = bo[0];
  float M1 = dec(*m1slot);
  float myc = coarse[lane];

  for (int rr = 0; rr < 8; ++rr) {
    int i = blockIdx.x * 32 + wid * 8 + rr;
    float s2i = s2[i];
    float th = -s2i;
    float z = s2i + M1;
    float mi = lrelu(z);
    float cA = __expf(z - mi);
    float cB = __expf(0.01f * s2i - mi);
    int n1 = __popcll(__ballot(myc < th));
    int cnt = 0;
    if (n1 > 0) {
      int L = (n1 - 1) * 128;
      float v2 = s1s[L + 1 + 2 * lane];
      int n2 = __popcll(__ballot(v2 < th));
      cnt = L + 2 * n2;
      if (cnt < NROW && s1s[cnt] < th) cnt++;
    }
    const float* ra = SufA + (size_t)cnt * LD65;
    const float* rb = PreB + (size_t)cnt * LD65;
    float vA = ra[lane], vB = rb[lane];
    float zA = ra[64],  zB = rb[64];
    float Z = cA * zA + cB * zB;
    float h2 = (cA * vA + cB * vB) / Z + h[(size_t)i * HD + lane];
    float acc = bfl;
#pragma unroll
    for (int q = 0; q < 16; ++q) {
      float4 wv = wf[q];
      int c = q * 4;
      acc += wv.x * __shfl(h2, c) + wv.y * __shfl(h2, c + 1) +
             wv.z * __shfl(h2, c + 2) + wv.w * __shfl(h2, c + 3);
    }
    float h3 = lrelu(acc);
    float pv = h3 * wol;
#pragma unroll
    for (int off = 32; off > 0; off >>= 1) pv += __shfl_xor(pv, off);
    if (lane == 0) out[i] = pv + bo0;
  }
}

extern "C" void kernel_launch(void* const* d_in, const int* in_sizes, int n_in,
                              void* d_out, int out_size, void* d_ws, size_t ws_size,
                              hipStream_t stream) {
  const float* x   = (const float*)d_in[0];
  const float* Wfc = (const float*)d_in[1];
  const float* bfc = (const float*)d_in[2];
  const float* Wtr = (const float*)d_in[3];
  const float* btr = (const float*)d_in[4];
  const float* a   = (const float*)d_in[5];
  const float* Wf  = (const float*)d_in[6];
  const float* bf  = (const float*)d_in[7];
  const float* Wo  = (const float*)d_in[8];
  const float* bo  = (const float*)d_in[9];
  float* out = (float*)d_out;

  char* w = (char*)d_ws;
  size_t off = 0;
  auto alloc = [&](size_t bytes) -> void* {
    void* p = w + off;
    off = (off + bytes + 255) & ~(size_t)255;
    return p;
  };
  float* h      = (float*)alloc((size_t)NROW * HD * 4);
  float* s1     = (float*)alloc(NROW * 4);
  float* s2     = (float*)alloc(NROW * 4);
  float* u12    = (float*)alloc(130 * 4);
  unsigned* m1  = (unsigned*)alloc(4);
  int* inv      = (int*)alloc(NROW * 4);
  float* s1s    = (float*)alloc(NROW * 4);
  unsigned short* Wh = (unsigned short*)alloc((size_t)64 * WK * 2);
  unsigned short* Wl = (unsigned short*)alloc((size_t)64 * WK * 2);
  float* hsT    = (float*)alloc((size_t)HD * NROW * 4);
  float* SufA   = (float*)alloc((size_t)(NROW + 1) * LD65 * 4);
  float* PreB   = (float*)alloc((size_t)(NROW + 1) * LD65 * 4);
  (void)in_sizes; (void)n_in; (void)out_size; (void)ws_size;

  k_prep<<<1 + (64 * WK) / 256, 256, 0, stream>>>(Wtr, btr, a, Wfc, u12, m1, Wh, Wl);
  k_gemm<<<NROW / 32, 512, 0, stream>>>(x, Wh, Wl, bfc, u12, h, s1, s2, m1);
  k_sort<<<NROW / 32, 512, 0, stream>>>(s1, s1s, inv);
  k_trans<<<NROW / 64, 256, 0, stream>>>(h, inv, hsT);
  k_scan<<<130, 512, 0, stream>>>(s1s, hsT, m1, SufA, PreB);
  k_final<<<NROW / 32, 256, 0, stream>>>(h, s1s, s2, SufA, PreB, m1, Wf, bf, Wo, bo, out);
}